// Round 2
// baseline (307.592 us; speedup 1.0000x reference)
//
#include <hip/hip_runtime.h>
#include <math.h>

#define NB   128
#define CF   1024
#define RR   256
#define NA   312
#define DV   300
#define M2   320
#define MT   640
#define NKC  32
#define NQ   160

typedef _Float16 half8  __attribute__((ext_vector_type(8)));
typedef _Float16 half4  __attribute__((ext_vector_type(4)));
typedef float float16v  __attribute__((ext_vector_type(16)));
typedef float float4v   __attribute__((ext_vector_type(4)));

// async global->LDS, 16B per lane. LDS dest must be wave-uniform base + lane*16,
// which holds for every use below (dest = smem_base + tid*16 + const).
__device__ __forceinline__ void gll16(const void* g, void* l) {
    __builtin_amdgcn_global_load_lds(
        (const __attribute__((address_space(1))) void*)g,
        (__attribute__((address_space(3))) void*)l, 16, 0, 0);
}

// ---- K1 fused:
//   blocks 0..159      : Q projection (160 blocks, vectorized W loads)
//   blocks 160..4255   : prep, one (b,kc) 32f x 256r chunk per block ----
__launch_bounds__(256, 6)
__global__ void k_pq(const float* __restrict__ img, float* __restrict__ ssq32,
                     _Float16* __restrict__ avT,
                     const float* __restrict__ V, const float* __restrict__ W1,
                     const float* __restrict__ W2, _Float16* __restrict__ Qb) {
    int lin = blockIdx.x;
    int t = threadIdx.x;
    if (lin >= NQ) {
        // ---------- prep ----------
        int m  = lin - NQ;
        int kc = m & 31;
        int b  = m >> 5;
        int kk8 = t & 3;          // 8-f group inside the 32-f chunk
        int rq  = t >> 2;         // r-quad: r = rq*4 .. rq*4+3
        const float* src = img + ((size_t)b * CF + kc * 32 + kk8 * 8) * RR + rq * 4;
        float4v v[8];
        #pragma unroll
        for (int j = 0; j < 8; ++j) v[j] = *(const float4v*)(src + (size_t)j * RR);
        float ss0 = 0.f, ss1 = 0.f, ss2 = 0.f, ss3 = 0.f;
        #pragma unroll
        for (int j = 0; j < 8; ++j) {
            ss0 += v[j][0] * v[j][0]; ss1 += v[j][1] * v[j][1];
            ss2 += v[j][2] * v[j][2]; ss3 += v[j][3] * v[j][3];
        }
        _Float16* dst = avT + ((size_t)(b * NKC + kc) * RR + rq * 4) * 32 + kk8 * 8;
        #pragma unroll
        for (int s = 0; s < 4; ++s) {
            half8 o;
            #pragma unroll
            for (int j = 0; j < 8; ++j) o[j] = (_Float16)v[j][s];
            *(half8*)(dst + (size_t)s * 32) = o;
        }
        // reduce over the 4 kk8 lanes (bits 0,1 of lane id)
        ss0 += __shfl_xor(ss0, 1, 64); ss0 += __shfl_xor(ss0, 2, 64);
        ss1 += __shfl_xor(ss1, 1, 64); ss1 += __shfl_xor(ss1, 2, 64);
        ss2 += __shfl_xor(ss2, 1, 64); ss2 += __shfl_xor(ss2, 2, 64);
        ss3 += __shfl_xor(ss3, 1, 64); ss3 += __shfl_xor(ss3, 2, 64);
        if (kk8 == 0) {
            float4v sv; sv[0] = ss0; sv[1] = ss1; sv[2] = ss2; sv[3] = ss3;
            *(float4v*)(ssq32 + ((size_t)b * NKC + kc) * RR + rq * 4) = sv;
        }
    } else {
        // ---------- Q projection: block = ib, covers all 1024 f ----------
        int ib = lin;
        bool isQ2 = ib >= 80;
        int i0l = (ib - (isQ2 ? 80 : 0)) * 4;
        int i0g = (isQ2 ? M2 : 0) + i0l;
        __shared__ float inv4[4];
        float acc[4][4];
        #pragma unroll
        for (int ii = 0; ii < 4; ++ii)
            #pragma unroll
            for (int j = 0; j < 4; ++j) acc[ii][j] = 0.f;
        if (i0l < NA) {
            int row = t >> 6, l64 = t & 63;
            float s = 0.f;
            for (int v = l64; v < DV; v += 64) { float x = V[(i0l + row) * DV + v]; s += x * x; }
            #pragma unroll
            for (int o = 32; o; o >>= 1) s += __shfl_xor(s, o, 64);
            if (l64 == 0) inv4[row] = 1.f / fmaxf(sqrtf(s), 1e-12f);
            __syncthreads();
            const float* W  = isQ2 ? W2 : W1;
            const float* Vb = V + (size_t)i0l * DV;
            for (int v = 0; v < DV; v += 2) {        // DV=300 even
                float4v w0 = *(const float4v*)(W + (size_t)v * CF + t * 4);
                float4v w1 = *(const float4v*)(W + (size_t)(v + 1) * CF + t * 4);
                #pragma unroll
                for (int ii = 0; ii < 4; ++ii) {
                    float a0 = Vb[(size_t)ii * DV + v];
                    float a1 = Vb[(size_t)ii * DV + v + 1];
                    #pragma unroll
                    for (int j = 0; j < 4; ++j) acc[ii][j] += a0 * w0[j] + a1 * w1[j];
                }
            }
            #pragma unroll
            for (int ii = 0; ii < 4; ++ii)
                #pragma unroll
                for (int j = 0; j < 4; ++j) acc[ii][j] *= inv4[ii];
        }
        int fg = t >> 3;            // (t*4) >> 5
        int fo = (t & 7) * 4;       // (t*4) & 31, 8B-aligned
        #pragma unroll
        for (int ii = 0; ii < 4; ++ii) {
            half4 h;
            #pragma unroll
            for (int j = 0; j < 4; ++j) h[j] = (_Float16)acc[ii][j];
            *(half4*)&Qb[((size_t)fg * MT + (i0g + ii)) * 32 + fo] = h;
        }
    }
}

// ---- K2: batched GEMM, M=128 x N=256, global_load_lds + counted vmcnt ----
__launch_bounds__(256, 3)
__global__ void k_gemm(const _Float16* __restrict__ Qb, const _Float16* __restrict__ avT,
                       const float* __restrict__ ssq32, float* __restrict__ out) {
    int lin  = blockIdx.x;
    int xcd  = lin & 7;
    int slot = lin >> 3;
    int bq   = slot / 5;
    int t2   = slot - bq * 5;
    int b    = bq * 8 + xcd;

    int tid = threadIdx.x;
    int lane = tid & 63, w = tid >> 6;
    int nl = lane & 31, kh = lane >> 5;

    __shared__ __align__(16) char smem[49152];
    _Float16* A0 = (_Float16*)smem;
    _Float16* A1 = (_Float16*)(smem + 8192);
    _Float16* B0 = (_Float16*)(smem + 16384);
    _Float16* B1 = (_Float16*)(smem + 32768);
    float* mred = (float*)smem;
    float* mg   = (float*)(smem + 1024);
    float* sred = (float*)(smem + 1280);
    float* dred = (float*)(smem + 2304);

    float16v acc[4][2];
    #pragma unroll
    for (int i = 0; i < 4; ++i)
        #pragma unroll
        for (int j = 0; j < 2; ++j)
            #pragma unroll
            for (int gi = 0; gi < 16; ++gi) acc[i][j][gi] = 0.f;

    int arow  = tid & 127;
    int akb0  = tid >> 7;
    int grow  = (arow < 64) ? (t2 * 64 + arow) : (M2 + t2 * 64 + (arow - 64));
    size_t a_src0 = (size_t)grow * 32 + akb0 * 8;
    const _Float16* bpanel = avT + (size_t)b * NKC * RR * 32;

    // 6 x 16B DMA per thread per stage: A tile 8KB + B tile 16KB, lane-linear dests
    #define STAGE(kc_, Ab, Bb) do {                                                  \
        const _Float16* as_ = Qb + (size_t)(kc_) * MT * 32 + a_src0;                 \
        gll16(as_,      (char*)(Ab) + tid * 16);                                     \
        gll16(as_ + 16, (char*)(Ab) + tid * 16 + 4096);                              \
        const _Float16* bs_ = bpanel + (size_t)(kc_) * RR * 32 + (size_t)tid * 32;   \
        gll16(bs_,      (char*)(Bb) + tid * 16);                                     \
        gll16(bs_ + 8,  (char*)(Bb) + tid * 16 + 4096);                              \
        gll16(bs_ + 16, (char*)(Bb) + tid * 16 + 8192);                              \
        gll16(bs_ + 24, (char*)(Bb) + tid * 16 + 12288);                             \
    } while (0)

    #define COMPUTE(Al, Bl) do {                                                     \
        _Pragma("unroll")                                                            \
        for (int ks = 0; ks < 2; ++ks) {                                             \
            int kb = ks * 2 + kh;                                                    \
            half8 b0f = *(const half8*)((Bl) + ((size_t)kb * 256 + w * 64 + nl) * 8);       \
            half8 b1f = *(const half8*)((Bl) + ((size_t)kb * 256 + w * 64 + 32 + nl) * 8);  \
            _Pragma("unroll")                                                        \
            for (int rf = 0; rf < 4; ++rf) {                                         \
                half8 af = *(const half8*)((Al) + ((size_t)kb * 128 + rf * 32 + nl) * 8);   \
                acc[rf][0] = __builtin_amdgcn_mfma_f32_32x32x16_f16(af, b0f, acc[rf][0], 0, 0, 0); \
                acc[rf][1] = __builtin_amdgcn_mfma_f32_32x32x16_f16(af, b1f, acc[rf][1], 0, 0, 0); \
            }                                                                        \
        }                                                                            \
    } while (0)

    STAGE(0, A0, B0);
    STAGE(1, A1, B1);
    asm volatile("s_waitcnt vmcnt(6)" ::: "memory");   // buf0 landed (mine)
    __builtin_amdgcn_s_barrier();                      // buf0 landed (all waves)
    __builtin_amdgcn_sched_barrier(0);

    #pragma unroll 1
    for (int kc = 0; kc < NKC - 2; kc += 2) {
        COMPUTE(A0, B0);                               // kc
        __builtin_amdgcn_s_barrier();                  // all done reading buf0
        __builtin_amdgcn_sched_barrier(0);
        STAGE(kc + 2, A0, B0);
        asm volatile("s_waitcnt vmcnt(6)" ::: "memory"); // kc+1 landed (mine)
        __builtin_amdgcn_s_barrier();                  // kc+1 landed (all)
        __builtin_amdgcn_sched_barrier(0);
        COMPUTE(A1, B1);                               // kc+1
        __builtin_amdgcn_s_barrier();                  // all done reading buf1
        __builtin_amdgcn_sched_barrier(0);
        STAGE(kc + 3, A1, B1);
        asm volatile("s_waitcnt vmcnt(6)" ::: "memory"); // kc+2 landed (mine)
        __builtin_amdgcn_s_barrier();                  // kc+2 landed (all)
        __builtin_amdgcn_sched_barrier(0);
    }
    COMPUTE(A0, B0);                                   // kc = 30
    asm volatile("s_waitcnt vmcnt(0)" ::: "memory");   // kc = 31 landed (mine)
    __builtin_amdgcn_s_barrier();                      // kc = 31 landed (all); also
    __builtin_amdgcn_sched_barrier(0);                 // fences epilogue smem reuse
    COMPUTE(A1, B1);                                   // kc = 31

    #undef STAGE
    #undef COMPUTE

    // inverse norms from the 32 per-kc sumsq partials (L2-resident, coalesced)
    const float* sq = ssq32 + (size_t)b * NKC * RR;
    int c0 = w * 64 + nl;
    float p0 = 0.f, p1 = 0.f;
    #pragma unroll
    for (int kc = 0; kc < NKC; ++kc) {
        p0 += sq[(size_t)kc * RR + c0];
        p1 += sq[(size_t)kc * RR + 32 + c0];
    }
    float iv0 = 1.f / fmaxf(sqrtf(p0), 1e-12f);
    float iv1 = 1.f / fmaxf(sqrtf(p1), 1e-12f);
    #pragma unroll
    for (int rf = 0; rf < 4; ++rf)
        #pragma unroll
        for (int gi = 0; gi < 16; ++gi) {
            acc[rf][0][gi] *= iv0;
            acc[rf][1][gi] *= iv1;
        }

    float mx[2][16];
    #pragma unroll
    for (int p = 0; p < 2; ++p)
        #pragma unroll
        for (int gi = 0; gi < 16; ++gi)
            mx[p][gi] = fmaxf(acc[p][0][gi], acc[p][1][gi]);
    #pragma unroll
    for (int off = 1; off <= 16; off <<= 1)
        #pragma unroll
        for (int p = 0; p < 2; ++p)
            #pragma unroll
            for (int gi = 0; gi < 16; ++gi)
                mx[p][gi] = fmaxf(mx[p][gi], __shfl_xor(mx[p][gi], off, 64));
    if (nl == 0) {
        #pragma unroll
        for (int p = 0; p < 2; ++p)
            #pragma unroll
            for (int gi = 0; gi < 16; ++gi) {
                int row = (gi & 3) + 8 * (gi >> 2) + 4 * kh;
                mred[(p * 32 + row) * 4 + w] = mx[p][gi];
            }
    }
    __syncthreads();
    if (tid < 64)
        mg[tid] = fmaxf(fmaxf(mred[tid * 4], mred[tid * 4 + 1]),
                        fmaxf(mred[tid * 4 + 2], mred[tid * 4 + 3]));
    __syncthreads();
    float sp[2][16], dp[2][16];
    #pragma unroll
    for (int p = 0; p < 2; ++p)
        #pragma unroll
        for (int gi = 0; gi < 16; ++gi) {
            int row = (gi & 3) + 8 * (gi >> 2) + 4 * kh;
            float m  = mg[p * 32 + row];
            float e0 = __expf(acc[p][0][gi] - m);
            float e1 = __expf(acc[p][1][gi] - m);
            sp[p][gi] = e0 + e1;
            dp[p][gi] = e0 * acc[p + 2][0][gi] + e1 * acc[p + 2][1][gi];
        }
    #pragma unroll
    for (int off = 1; off <= 16; off <<= 1)
        #pragma unroll
        for (int p = 0; p < 2; ++p)
            #pragma unroll
            for (int gi = 0; gi < 16; ++gi) {
                sp[p][gi] += __shfl_xor(sp[p][gi], off, 64);
                dp[p][gi] += __shfl_xor(dp[p][gi], off, 64);
            }
    if (nl == 0) {
        #pragma unroll
        for (int p = 0; p < 2; ++p)
            #pragma unroll
            for (int gi = 0; gi < 16; ++gi) {
                int row = (gi & 3) + 8 * (gi >> 2) + 4 * kh;
                sred[(p * 32 + row) * 4 + w] = sp[p][gi];
                dred[(p * 32 + row) * 4 + w] = dp[p][gi];
            }
    }
    __syncthreads();
    if (tid < 64) {
        float s = sred[tid * 4] + sred[tid * 4 + 1] + sred[tid * 4 + 2] + sred[tid * 4 + 3];
        float d = dred[tid * 4] + dred[tid * 4 + 1] + dred[tid * 4 + 2] + dred[tid * 4 + 3];
        int ig = t2 * 64 + tid;
        if (ig < NA) out[b * NA + ig] = d / s;
    }
}

// ---- launcher ----
extern "C" void kernel_launch(void* const* d_in, const int* in_sizes, int n_in,
                              void* d_out, int out_size, void* d_ws, size_t ws_size,
                              hipStream_t stream) {
    const float* img = (const float*)d_in[0];
    const float* V   = (const float*)d_in[1];
    const float* W1  = (const float*)d_in[2];
    const float* W2  = (const float*)d_in[3];
    float* out = (float*)d_out;

    char* ws = (char*)d_ws;
    size_t off = 0;
    float*    ssq32 = (float*)(ws + off);    off += (size_t)NB * NKC * RR * 4;
    _Float16* avT   = (_Float16*)(ws + off); off += (size_t)NB * CF * RR * 2;
    _Float16* Qb    = (_Float16*)(ws + off); off += (size_t)NKC * MT * 32 * 2;

    k_pq<<<dim3(NQ + NB * NKC), 256, 0, stream>>>(img, ssq32, avT, V, W1, W2, Qb);
    k_gemm<<<dim3(640), 256, 0, stream>>>(Qb, avT, ssq32, out);
}

// Round 3
// 283.173 us; speedup vs baseline: 1.0862x; 1.0862x over previous
//
#include <hip/hip_runtime.h>
#include <math.h>

#define NB   128
#define CF   1024
#define RR   256
#define NA   312
#define DV   300
#define MT   640
#define NKC  32
#define NQ   160

typedef _Float16 half8  __attribute__((ext_vector_type(8)));
typedef _Float16 half4  __attribute__((ext_vector_type(4)));
typedef float float16v  __attribute__((ext_vector_type(16)));
typedef float float4v   __attribute__((ext_vector_type(4)));

// async global->LDS, 16B per lane; LDS dest = wave-uniform base + lane*16.
__device__ __forceinline__ void gll16(const void* g, void* l) {
    __builtin_amdgcn_global_load_lds(
        (const __attribute__((address_space(1))) void*)g,
        (__attribute__((address_space(3))) void*)l, 16, 0, 0);
}

// ---- K1 fused:
//   blocks 0..159    : Q projection (pair-interleaved Qb rows)
//   blocks 160..4255 : prep, one (b,kc) 32f x 256r chunk per block ----
__launch_bounds__(256, 6)
__global__ void k_pq(const float* __restrict__ img, float* __restrict__ ssq32,
                     _Float16* __restrict__ avT,
                     const float* __restrict__ V, const float* __restrict__ W1,
                     const float* __restrict__ W2, _Float16* __restrict__ Qb) {
    int lin = blockIdx.x;
    int t = threadIdx.x;
    if (lin >= NQ) {
        // ---------- prep ----------
        int m  = lin - NQ;
        int kc = m & 31;
        int b  = m >> 5;
        int kk8 = t & 3;          // 8-f group inside the 32-f chunk
        int rq  = t >> 2;         // r-quad
        const float* src = img + ((size_t)b * CF + kc * 32 + kk8 * 8) * RR + rq * 4;
        float4v v[8];
        #pragma unroll
        for (int j = 0; j < 8; ++j) v[j] = *(const float4v*)(src + (size_t)j * RR);
        float ss0 = 0.f, ss1 = 0.f, ss2 = 0.f, ss3 = 0.f;
        #pragma unroll
        for (int j = 0; j < 8; ++j) {
            ss0 += v[j][0] * v[j][0]; ss1 += v[j][1] * v[j][1];
            ss2 += v[j][2] * v[j][2]; ss3 += v[j][3] * v[j][3];
        }
        _Float16* dst = avT + ((size_t)(b * NKC + kc) * RR + rq * 4) * 32 + kk8 * 8;
        #pragma unroll
        for (int s = 0; s < 4; ++s) {
            half8 o;
            #pragma unroll
            for (int j = 0; j < 8; ++j) o[j] = (_Float16)v[j][s];
            *(half8*)(dst + (size_t)s * 32) = o;
        }
        ss0 += __shfl_xor(ss0, 1, 64); ss0 += __shfl_xor(ss0, 2, 64);
        ss1 += __shfl_xor(ss1, 1, 64); ss1 += __shfl_xor(ss1, 2, 64);
        ss2 += __shfl_xor(ss2, 1, 64); ss2 += __shfl_xor(ss2, 2, 64);
        ss3 += __shfl_xor(ss3, 1, 64); ss3 += __shfl_xor(ss3, 2, 64);
        if (kk8 == 0) {
            float4v sv; sv[0] = ss0; sv[1] = ss1; sv[2] = ss2; sv[3] = ss3;
            *(float4v*)(ssq32 + ((size_t)b * NKC + kc) * RR + rq * 4) = sv;
        }
    } else {
        // ---------- Q projection ----------
        int ib = lin;
        bool isQ2 = ib >= 80;
        int i0l = (ib - (isQ2 ? 80 : 0)) * 4;     // pair base 0..316
        __shared__ float inv4[4];
        float acc[4][4];
        #pragma unroll
        for (int ii = 0; ii < 4; ++ii)
            #pragma unroll
            for (int j = 0; j < 4; ++j) acc[ii][j] = 0.f;
        if (i0l < NA) {
            int row = t >> 6, l64 = t & 63;
            float s = 0.f;
            for (int v = l64; v < DV; v += 64) { float x = V[(i0l + row) * DV + v]; s += x * x; }
            #pragma unroll
            for (int o = 32; o; o >>= 1) s += __shfl_xor(s, o, 64);
            if (l64 == 0) inv4[row] = 1.f / fmaxf(sqrtf(s), 1e-12f);
            __syncthreads();
            const float* W  = isQ2 ? W2 : W1;
            const float* Vb = V + (size_t)i0l * DV;
            for (int v = 0; v < DV; v += 2) {
                float4v w0 = *(const float4v*)(W + (size_t)v * CF + t * 4);
                float4v w1 = *(const float4v*)(W + (size_t)(v + 1) * CF + t * 4);
                #pragma unroll
                for (int ii = 0; ii < 4; ++ii) {
                    float a0 = Vb[(size_t)ii * DV + v];
                    float a1 = Vb[(size_t)ii * DV + v + 1];
                    #pragma unroll
                    for (int j = 0; j < 4; ++j) acc[ii][j] += a0 * w0[j] + a1 * w1[j];
                }
            }
            #pragma unroll
            for (int ii = 0; ii < 4; ++ii)
                #pragma unroll
                for (int j = 0; j < 4; ++j) acc[ii][j] *= inv4[ii];
        }
        int fg = t >> 3;
        int fo = (t & 7) * 4;
        int q12 = isQ2 ? 1 : 0;
        #pragma unroll
        for (int ii = 0; ii < 4; ++ii) {
            half4 h;
            #pragma unroll
            for (int j = 0; j < 4; ++j) h[j] = (_Float16)acc[ii][j];
            *(half4*)&Qb[((size_t)fg * MT + (2 * (i0l + ii) + q12)) * 32 + fo] = h;
        }
    }
}

// ---- K2: one block per (b, half): M=320 x N=256, 8 waves, 3-buf pipeline ----
extern __shared__ char smem[];
__launch_bounds__(512, 2)
__global__ void k_gemm(const _Float16* __restrict__ Qb, const _Float16* __restrict__ avT,
                       const float* __restrict__ ssq32, float* __restrict__ out) {
    int lin = blockIdx.x;              // 0..255
    int xcd = lin & 7;
    int u   = lin >> 3;                // 0..31
    int b   = xcd + 8 * (u & 15);      // both halves of b share an XCD
    int t2h = u >> 4;                  // 0/1: pair range [t2h*160, +160)

    int tid  = threadIdx.x;
    int lane = tid & 63;
    int w    = tid >> 6;               // 0..7
    int wm   = w >> 2;                 // 0..1  (M split: 160 rows each)
    int wn   = w & 3;                  // 0..3  (N split: 64 cols each)
    int nl   = lane & 31;
    int kh   = lane >> 5;

    // chunk-linear staging addresses (A: [kb4][320 rows][16B], B: [kb4][256 rows][16B])
    int c1 = 512 + tid;
    int a_s0 = (tid % 320) * 64 + (tid / 320) * 16;
    int a_s1 = (c1 % 320) * 64 + (c1 / 320) * 16;
    int a_s2 = ((tid & 255) + 64) * 64 + 3 * 16;        // c2 = 1024 + (tid&255)
    int a_d0 = tid * 16;
    int a_d1 = a_d0 + 8192;
    int a_d2 = 16384 + (tid & 255) * 16;                // waves 4-7 duplicate (same data)
    int b_s0 = (tid & 255) * 64 + (tid >> 8) * 16;

    const char* Abase_g = (const char*)Qb;
    const char* Bbase_g = (const char*)avT + ((size_t)b * NKC) * RR * 64;

    float16v acc[5][2];
    #pragma unroll
    for (int i = 0; i < 5; ++i)
        #pragma unroll
        for (int j = 0; j < 2; ++j)
            #pragma unroll
            for (int gi = 0; gi < 16; ++gi) acc[i][j][gi] = 0.f;

    char* p0 = smem;                 // read buffer (kc % 3)
    char* p1 = smem + 36864;
    char* p2 = smem + 73728;         // stage target (kc+2)

    #define STAGE(kc_, buf) do {                                                   \
        int kcl = (kc_) < NKC ? (kc_) : (NKC - 1);                                 \
        const char* aS = Abase_g + ((size_t)kcl * MT + (size_t)t2h * 320) * 64;    \
        const char* bS = Bbase_g + (size_t)kcl * RR * 64;                          \
        char* ab = (buf); char* bb = (buf) + 20480;                                \
        gll16(aS + a_s0, ab + a_d0);                                               \
        gll16(aS + a_s1, ab + a_d1);                                               \
        gll16(aS + a_s2, ab + a_d2);                                               \
        gll16(bS + b_s0,      bb + tid * 16);                                      \
        gll16(bS + b_s0 + 32, bb + tid * 16 + 8192);                               \
    } while (0)

    #define COMPUTE(buf) do {                                                      \
        const char* Al = (buf); const char* Bl = (buf) + 20480;                    \
        _Pragma("unroll")                                                          \
        for (int ks = 0; ks < 2; ++ks) {                                           \
            int kb = ks * 2 + kh;                                                  \
            half8 bf0 = *(const half8*)(Bl + ((size_t)kb * 256 + wn * 64 + nl) * 16);      \
            half8 bf1 = *(const half8*)(Bl + ((size_t)kb * 256 + wn * 64 + 32 + nl) * 16); \
            _Pragma("unroll")                                                      \
            for (int mt = 0; mt < 5; ++mt) {                                       \
                half8 af = *(const half8*)(Al + ((size_t)kb * 320 + wm * 160 + mt * 32 + nl) * 16); \
                acc[mt][0] = __builtin_amdgcn_mfma_f32_32x32x16_f16(af, bf0, acc[mt][0], 0, 0, 0);  \
                acc[mt][1] = __builtin_amdgcn_mfma_f32_32x32x16_f16(af, bf1, acc[mt][1], 0, 0, 0);  \
            }                                                                      \
        }                                                                          \
    } while (0)

    STAGE(0, p0);
    __builtin_amdgcn_sched_barrier(0);
    STAGE(1, p1);
    asm volatile("s_waitcnt vmcnt(5)" ::: "memory");   // stage(0) landed (mine)
    __builtin_amdgcn_s_barrier();                      // stage(0) landed (all)
    __builtin_amdgcn_sched_barrier(0);

    #pragma unroll 1
    for (int kc = 0; kc < NKC; ++kc) {
        STAGE(kc + 2, p2);                             // overwrites buf read at kc-1 (safe: post-barrier)
        asm volatile("s_waitcnt vmcnt(5)" ::: "memory"); // stage(kc+1) landed (mine)
        __builtin_amdgcn_sched_barrier(0);
        COMPUTE(p0);                                   // reads stage(kc), certified last phase
        __builtin_amdgcn_sched_barrier(0);
        __builtin_amdgcn_s_barrier();                  // all done reading buf kc; stage(kc+1) landed (all)
        char* tmp = p0; p0 = p1; p1 = p2; p2 = tmp;
    }
    asm volatile("s_waitcnt vmcnt(0)" ::: "memory");
    __builtin_amdgcn_s_barrier();
    __builtin_amdgcn_sched_barrier(0);
    #undef STAGE
    #undef COMPUTE

    // ---- epilogue: invg scale, softmax over r, dot with Q2 rows ----
    float* mred = (float*)smem;             // [4][160]
    float* mg   = (float*)(smem + 2560);    // [160]
    float* sred = (float*)(smem + 3200);    // [4][160]
    float* dred = (float*)(smem + 5760);    // [4][160]

    const float* sq = ssq32 + (size_t)b * NKC * RR;
    int c0 = wn * 64 + nl;
    float q0 = 0.f, q1 = 0.f;
    #pragma unroll
    for (int kc = 0; kc < NKC; ++kc) {
        q0 += sq[(size_t)kc * RR + c0];
        q1 += sq[(size_t)kc * RR + 32 + c0];
    }
    float iv0 = 1.f / fmaxf(sqrtf(q0), 1e-12f);
    float iv1 = 1.f / fmaxf(sqrtf(q1), 1e-12f);
    #pragma unroll
    for (int mt = 0; mt < 5; ++mt)
        #pragma unroll
        for (int gi = 0; gi < 16; ++gi) {
            acc[mt][0][gi] *= iv0;
            acc[mt][1][gi] *= iv1;
        }

    // pass 1: per-pair max over r
    #pragma unroll
    for (int mt = 0; mt < 5; ++mt) {
        #pragma unroll
        for (int e = 0; e < 8; ++e) {
            int g = 2 * e;
            float mx = fmaxf(acc[mt][0][g], acc[mt][1][g]);
            #pragma unroll
            for (int off = 1; off <= 16; off <<= 1)
                mx = fmaxf(mx, __shfl_xor(mx, off, 64));
            if (nl == 0) {
                int row = (g & 3) + 8 * (g >> 2) + 4 * kh;   // even
                mred[wn * 160 + wm * 80 + mt * 16 + (row >> 1)] = mx;
            }
        }
    }
    __syncthreads();
    if (tid < 160)
        mg[tid] = fmaxf(fmaxf(mred[tid], mred[160 + tid]),
                        fmaxf(mred[320 + tid], mred[480 + tid]));
    __syncthreads();

    // pass 2: exp-sum and weighted Q2 dot
    #pragma unroll
    for (int mt = 0; mt < 5; ++mt) {
        #pragma unroll
        for (int e = 0; e < 8; ++e) {
            int g = 2 * e;
            int row = (g & 3) + 8 * (g >> 2) + 4 * kh;
            int Pl = wm * 80 + mt * 16 + (row >> 1);
            float m = mg[Pl];
            float e0 = __expf(acc[mt][0][g] - m);
            float e1 = __expf(acc[mt][1][g] - m);
            float s = e0 + e1;
            float d = e0 * acc[mt][0][g + 1] + e1 * acc[mt][1][g + 1];
            #pragma unroll
            for (int off = 1; off <= 16; off <<= 1) {
                s += __shfl_xor(s, off, 64);
                d += __shfl_xor(d, off, 64);
            }
            if (nl == 0) {
                sred[wn * 160 + Pl] = s;
                dred[wn * 160 + Pl] = d;
            }
        }
    }
    __syncthreads();
    if (tid < 160) {
        float s = sred[tid] + sred[160 + tid] + sred[320 + tid] + sred[480 + tid];
        float d = dred[tid] + dred[160 + tid] + dred[320 + tid] + dred[480 + tid];
        int ig = t2h * 160 + tid;
        if (ig < NA) out[b * NA + ig] = d / s;
    }
}

// ---- launcher ----
extern "C" void kernel_launch(void* const* d_in, const int* in_sizes, int n_in,
                              void* d_out, int out_size, void* d_ws, size_t ws_size,
                              hipStream_t stream) {
    const float* img = (const float*)d_in[0];
    const float* V   = (const float*)d_in[1];
    const float* W1  = (const float*)d_in[2];
    const float* W2  = (const float*)d_in[3];
    float* out = (float*)d_out;

    char* ws = (char*)d_ws;
    size_t off = 0;
    float*    ssq32 = (float*)(ws + off);    off += (size_t)NB * NKC * RR * 4;
    _Float16* avT   = (_Float16*)(ws + off); off += (size_t)NB * CF * RR * 2;
    _Float16* Qb    = (_Float16*)(ws + off); off += (size_t)NKC * MT * 32 * 2;

    static bool attr_done = false;
    if (!attr_done) {
        hipFuncSetAttribute((const void*)k_gemm,
                            hipFuncAttributeMaxDynamicSharedMemorySize, 110592);
        attr_done = true;
    }

    k_pq<<<dim3(NQ + NB * NKC), 256, 0, stream>>>(img, ssq32, avT, V, W1, W2, Qb);
    k_gemm<<<dim3(256), 512, 110592, stream>>>(Qb, avT, ssq32, out);
}